// Round 1
// baseline (587.670 us; speedup 1.0000x reference)
//
#include <hip/hip_runtime.h>

#define NPTS 12288
#define DIMS 8
#define EPS2 0.25f
#define MINS 5
#define TI   256            // i-points per block (1 per thread)
#define SUBT 256            // j-subtile staged in LDS
#define NJB  16             // j-chunks (grid.y)
#define JCHUNK (NPTS / NJB) // 768
#define NIB  (NPTS / TI)    // 48
#define SENT NPTS

// ---------------- lock-free union-find (device-scope atomics) ----------------

__device__ __forceinline__ int uf_load(int* p, int i) {
  return __hip_atomic_load(&p[i], __ATOMIC_RELAXED, __HIP_MEMORY_SCOPE_AGENT);
}

__device__ int uf_find(int* parent, int v) {
  int p = uf_load(parent, v);
  while (p != v) {
    int gp = uf_load(parent, p);
    if (gp != p) {
      // path halving; benign race (always writes a valid ancestor)
      __hip_atomic_store(&parent[v], gp, __ATOMIC_RELAXED, __HIP_MEMORY_SCOPE_AGENT);
    }
    v = p; p = gp;
  }
  return v;
}

__device__ void uf_union(int* parent, int a, int b) {
  while (true) {
    a = uf_find(parent, a);
    b = uf_find(parent, b);
    if (a == b) return;
    int lo = min(a, b), hi = max(a, b);
    int old = atomicCAS(&parent[hi], hi, lo);  // hook larger root under smaller
    if (old == hi) return;
    a = lo; b = hi;  // lost race; re-resolve
  }
}

// ---------------- kernels ----------------

__global__ __launch_bounds__(256) void k_init(const float* __restrict__ X,
                                              float* __restrict__ sq,
                                              int* __restrict__ density,
                                              int* __restrict__ parent) {
  int i = blockIdx.x * blockDim.x + threadIdx.x;
  if (i >= NPTS) return;
  float s = 0.f;
#pragma unroll
  for (int d = 0; d < DIMS; d++) { float x = X[i * DIMS + d]; s = fmaf(x, x, s); }
  sq[i] = s;
  density[i] = 0;
  parent[i] = i;
}

__global__ __launch_bounds__(256) void k_density(const float* __restrict__ X,
                                                 const float* __restrict__ sq,
                                                 int* __restrict__ density) {
  __shared__ float xs[SUBT][DIMS];
  __shared__ float sqs[SUBT];
  int t = threadIdx.x;
  int i = blockIdx.x * TI + t;
  float xi[DIMS];
#pragma unroll
  for (int d = 0; d < DIMS; d++) xi[d] = X[i * DIMS + d];
  float sqi = sq[i];
  int j0 = blockIdx.y * JCHUNK;
  int count = 0;
  for (int js = 0; js < JCHUNK; js += SUBT) {
    __syncthreads();
    {
      int j = j0 + js + t;
      float4 a = ((const float4*)X)[j * 2];
      float4 b = ((const float4*)X)[j * 2 + 1];
      xs[t][0] = a.x; xs[t][1] = a.y; xs[t][2] = a.z; xs[t][3] = a.w;
      xs[t][4] = b.x; xs[t][5] = b.y; xs[t][6] = b.z; xs[t][7] = b.w;
      sqs[t] = sq[j];
    }
    __syncthreads();
#pragma unroll 4
    for (int jj = 0; jj < SUBT; jj++) {
      float dot = 0.f;
#pragma unroll
      for (int d = 0; d < DIMS; d++) dot = fmaf(xi[d], xs[jj][d], dot);
      float d2 = (sqi + sqs[jj]) - 2.0f * dot;   // 2*dot exact -> rounding matches ref
      count += (d2 <= EPS2) ? 1 : 0;
    }
  }
  atomicAdd(&density[i], count);
}

__global__ __launch_bounds__(256) void k_union_pass(const float* __restrict__ X,
                                                    const float* __restrict__ sq,
                                                    const int* __restrict__ density,
                                                    int* __restrict__ parent) {
  __shared__ float xs[SUBT][DIMS];
  __shared__ float sqs[SUBT];
  __shared__ int dns[SUBT];
  int t = threadIdx.x;
  int i = blockIdx.x * TI + t;
  bool rowActive = (density[i] >= MINS);
  float xi[DIMS];
#pragma unroll
  for (int d = 0; d < DIMS; d++) xi[d] = X[i * DIMS + d];
  float sqi = sq[i];
  int j0 = blockIdx.y * JCHUNK;
  for (int js = 0; js < JCHUNK; js += SUBT) {
    __syncthreads();
    {
      int j = j0 + js + t;
      float4 a = ((const float4*)X)[j * 2];
      float4 b = ((const float4*)X)[j * 2 + 1];
      xs[t][0] = a.x; xs[t][1] = a.y; xs[t][2] = a.z; xs[t][3] = a.w;
      xs[t][4] = b.x; xs[t][5] = b.y; xs[t][6] = b.z; xs[t][7] = b.w;
      sqs[t] = sq[j];
      dns[t] = density[j];
    }
    __syncthreads();
    if (!rowActive) continue;
#pragma unroll 4
    for (int jj = 0; jj < SUBT; jj++) {
      int jg = j0 + js + jj;
      float dot = 0.f;
#pragma unroll
      for (int d = 0; d < DIMS; d++) dot = fmaf(xi[d], xs[jj][d], dot);
      float d2 = (sqi + sqs[jj]) - 2.0f * dot;
      if (jg > i && d2 <= EPS2 && dns[jj] >= MINS) uf_union(parent, i, jg);
    }
  }
}

__global__ __launch_bounds__(256) void k_flatten(const int* __restrict__ density,
                                                 int* __restrict__ parent,
                                                 int* __restrict__ root,
                                                 int* __restrict__ is_root) {
  int i = blockIdx.x * blockDim.x + threadIdx.x;
  if (i >= NPTS) return;
  if (density[i] >= MINS) {
    int r = uf_find(parent, i);
    root[i] = r;
    is_root[i] = (r == i) ? 1 : 0;
  } else {
    root[i] = SENT;   // border pass will atomicMin into this
    is_root[i] = 0;
  }
}

__global__ __launch_bounds__(256) void k_border(const float* __restrict__ X,
                                                const float* __restrict__ sq,
                                                const int* __restrict__ density,
                                                int* __restrict__ root) {
  __shared__ float xs[SUBT][DIMS];
  __shared__ float sqs[SUBT];
  __shared__ int dns[SUBT];
  __shared__ int rts[SUBT];
  int t = threadIdx.x;
  int i = blockIdx.x * TI + t;
  bool rowActive = (density[i] < MINS);
  if (__syncthreads_count(rowActive ? 1 : 0) == 0) return;  // all-core block: skip
  float xi[DIMS];
#pragma unroll
  for (int d = 0; d < DIMS; d++) xi[d] = X[i * DIMS + d];
  float sqi = sq[i];
  int j0 = blockIdx.y * JCHUNK;
  int m = SENT;
  for (int js = 0; js < JCHUNK; js += SUBT) {
    __syncthreads();
    {
      int j = j0 + js + t;
      float4 a = ((const float4*)X)[j * 2];
      float4 b = ((const float4*)X)[j * 2 + 1];
      xs[t][0] = a.x; xs[t][1] = a.y; xs[t][2] = a.z; xs[t][3] = a.w;
      xs[t][4] = b.x; xs[t][5] = b.y; xs[t][6] = b.z; xs[t][7] = b.w;
      sqs[t] = sq[j];
      dns[t] = density[j];
      rts[t] = root[j];   // valid (stable) only where dns>=MINS; guarded below
    }
    __syncthreads();
    if (!rowActive) continue;
#pragma unroll 4
    for (int jj = 0; jj < SUBT; jj++) {
      float dot = 0.f;
#pragma unroll
      for (int d = 0; d < DIMS; d++) dot = fmaf(xi[d], xs[jj][d], dot);
      float d2 = (sqi + sqs[jj]) - 2.0f * dot;
      if (d2 <= EPS2 && dns[jj] >= MINS) m = min(m, rts[jj]);
    }
  }
  if (rowActive && m < SENT) atomicMin(&root[i], m);
}

// rank = inclusive cumsum(is_root) - 1, single block
__global__ __launch_bounds__(1024) void k_scan(const int* __restrict__ is_root,
                                               int* __restrict__ rank) {
  __shared__ int buf[1024];
  __shared__ int carry;
  int t = threadIdx.x;
  if (t == 0) carry = 0;
  __syncthreads();
  for (int base = 0; base < NPTS; base += 1024) {
    int v = is_root[base + t];
    buf[t] = v;
    __syncthreads();
    for (int off = 1; off < 1024; off <<= 1) {
      int add = (t >= off) ? buf[t - off] : 0;
      __syncthreads();
      buf[t] += add;
      __syncthreads();
    }
    int inc = buf[t] + carry;
    rank[base + t] = inc - 1;
    __syncthreads();
    if (t == 1023) carry = inc;
    __syncthreads();
  }
}

__global__ __launch_bounds__(256) void k_final(const int* __restrict__ root,
                                               const int* __restrict__ rank,
                                               float* __restrict__ out) {
  int i = blockIdx.x * blockDim.x + threadIdx.x;
  if (i >= NPTS) return;
  int r = root[i];
  out[i] = (r < SENT) ? (float)rank[r] : -1.0f;
}

// ---------------- launch ----------------

extern "C" void kernel_launch(void* const* d_in, const int* in_sizes, int n_in,
                              void* d_out, int out_size, void* d_ws, size_t ws_size,
                              hipStream_t stream) {
  const float* X = (const float*)d_in[0];
  float* out = (float*)d_out;

  char* ws = (char*)d_ws;
  float* sq      = (float*)(ws);
  int*   density = (int*)(ws + 4 * NPTS);
  int*   parent  = (int*)(ws + 8 * NPTS);
  int*   root    = (int*)(ws + 12 * NPTS);
  int*   is_root = (int*)(ws + 16 * NPTS);
  int*   rank    = (int*)(ws + 20 * NPTS);

  dim3 grid2(NIB, NJB);

  k_init<<<NIB, 256, 0, stream>>>(X, sq, density, parent);
  k_density<<<grid2, 256, 0, stream>>>(X, sq, density);
  k_union_pass<<<grid2, 256, 0, stream>>>(X, sq, density, parent);
  k_flatten<<<NIB, 256, 0, stream>>>(density, parent, root, is_root);
  k_border<<<grid2, 256, 0, stream>>>(X, sq, density, root);
  k_scan<<<1, 1024, 0, stream>>>(is_root, rank);
  k_final<<<NIB, 256, 0, stream>>>(root, rank, out);
}